// Round 11
// baseline (323.873 us; speedup 1.0000x reference)
//
#include <hip/hip_runtime.h>

#define B_ 2
#define D_ 32
#define C_ 256
#define T_ 64
#define TE_ 1024
#define H_ 8
#define N_ 64   // B_*D_
#define NBLK 512

typedef __attribute__((ext_vector_type(8))) short bf16x8;
typedef __attribute__((ext_vector_type(8))) unsigned short u16x8;
typedef __attribute__((ext_vector_type(4))) float f32x4;

__device__ inline ushort f2bf(float x){
  unsigned u = __float_as_uint(x);
  unsigned r = u + 0x7FFFu + ((u>>16)&1u);
  return (ushort)(r>>16);
}
__device__ inline float bf2f(ushort u){
  return __uint_as_float(((unsigned)u)<<16);
}

// Grid-wide barrier: one slot per sync point, zeroed by hipMemsetAsync before
// launch. Release-RMW + acquire-spin at agent scope. BOUNDED spin: if blocks
// are not co-resident the kernel exits (fast failing bench, not a hang).
// Co-residency is guaranteed by __launch_bounds__(256,2): VGPR<=256 ->
// 2 blocks/CU x 256 CUs = 512 = NBLK; LDS 2x20.6KB=41KB << 160KB.
__device__ inline bool gsync(int* bar, int slot){
  __syncthreads();
  __shared__ int ok;
  if (threadIdx.x == 0){
    __threadfence();
    __hip_atomic_fetch_add(&bar[slot], 1, __ATOMIC_ACQ_REL, __HIP_MEMORY_SCOPE_AGENT);
    int spins = 0; ok = 1;
    while (__hip_atomic_load(&bar[slot], __ATOMIC_ACQUIRE, __HIP_MEMORY_SCOPE_AGENT) < NBLK){
      __builtin_amdgcn_s_sleep(2);
      if (++spins > 50000000) { ok = 0; break; }
    }
  }
  __syncthreads();
  return ok != 0;
}

// ---------------------------------------------------------------- stage bodies

__device__ inline void prep_tile(int blk, int tid, char* smemc,
    const float* __restrict__ w_qkv, const float* __restrict__ wp,
    const float* __restrict__ w3,
    ushort* __restrict__ wqb, ushort* __restrict__ wpr, ushort* __restrict__ w3b,
    const float* __restrict__ x, const float* __restrict__ nsc,
    const float* __restrict__ nbi, ushort* __restrict__ ht,
    const float* __restrict__ temb, const float* __restrict__ w2,
    const float* __restrict__ b2, float* __restrict__ tp)
{
  float* smem = (float*)smemc;
  if (blk < 320) {
    if (blk < 192) {
      int i = blk*256 + tid;
      float4 v = ((const float4*)w_qkv)[i];
      ushort4 o; o.x=f2bf(v.x); o.y=f2bf(v.y); o.z=f2bf(v.z); o.w=f2bf(v.w);
      ((ushort4*)wqb)[i] = o;
    } else if (blk < 256) {
      // wp [o][c] -> Wr [o][(c&7)*32 + (c>>3)]
      int i = (blk-192)*256 + tid;
      float4 v = ((const float4*)wp)[i];
      int o = i >> 6, c0 = (i & 63)*4;
      #pragma unroll
      for (int e=0;e<4;e++){
        int c = c0+e;
        float vv = (e==0)?v.x:(e==1)?v.y:(e==2)?v.z:v.w;
        wpr[o*256 + (c&7)*32 + (c>>3)] = f2bf(vv);
      }
    } else {
      int i = (blk-256)*256 + tid;
      float4 v = ((const float4*)w3)[i];
      ushort4 o; o.x=f2bf(v.x); o.y=f2bf(v.y); o.z=f2bf(v.z); o.w=f2bf(v.w);
      ((ushort4*)w3b)[i] = o;
    }
    return;
  }
  if (blk < 2368) {
    // group norm: x (N,256,64) -> ht bf16 [n][t][c], 16B stores
    int b2k = blk - 320;
    int n = b2k >> 5, g = b2k & 31;
    const float* xp = x + ((size_t)n*C_ + g*8) * T_;
    float v0 = xp[tid], v1 = xp[tid+256];
    float s = v0+v1, ss = v0*v0 + v1*v1;
    #pragma unroll
    for (int off=32; off; off>>=1) { s += __shfl_down(s,off); ss += __shfl_down(ss,off); }
    float* red = smem;
    ushort* gbuf = (ushort*)(smem + 16);
    int wid = tid>>6, lane = tid&63;
    if (lane==0){ red[wid]=s; red[4+wid]=ss; }
    __syncthreads();
    if (tid==0){
      float a  = red[0]+red[1]+red[2]+red[3];
      float bb = red[4]+red[5]+red[6]+red[7];
      float mean = a*(1.f/512.f);
      float var  = bb*(1.f/512.f) - mean*mean;
      red[8]=mean; red[9]=rsqrtf(var + 1e-5f);
    }
    __syncthreads();
    float mean = red[8], inv = red[9];
    int t = tid & 63, w = tid >> 6;
    int c0 = g*8 + w, c1 = c0 + 4;
    gbuf[w*64 + t]     = f2bf((v0-mean)*inv*nsc[c0] + nbi[c0]);
    gbuf[(w+4)*64 + t] = f2bf((v1-mean)*inv*nsc[c1] + nbi[c1]);
    __syncthreads();
    if (tid < 64){
      u16x8 pk;
      #pragma unroll
      for (int i=0;i<8;i++) pk[i] = gbuf[i*64 + tid];
      *(u16x8*)&ht[((size_t)n*T_ + tid)*C_ + g*8] = pk;
    }
    return;
  }
  // tproj
  {
    int b3k = blk - 2368;
    int b = b3k >> 6, ob = b3k & 63;
    float* w2s = smem;                  // 16 KB
    float* red = smem + 4096;           // 4 KB
    const float* w2p = w2 + (size_t)ob*4*1024;
    #pragma unroll
    for (int r = 0; r < 16; r++) w2s[r*256 + tid] = w2p[r*256 + tid];
    __syncthreads();
    int t = tid & 63, eq = tid >> 6;
    const float* tep = temb + ((size_t)b*1024 + eq*256)*64 + t;
    const float* wq  = w2s + eq*256;
    float acc[4] = {0.f,0.f,0.f,0.f};
    #pragma unroll 4
    for (int i = 0; i < 256; i += 4) {
      float tv0 = tep[(i+0)*64];
      float tv1 = tep[(i+1)*64];
      float tv2 = tep[(i+2)*64];
      float tv3 = tep[(i+3)*64];
      #pragma unroll
      for (int j = 0; j < 4; j++) {
        float4 w4 = *(const float4*)&wq[j*1024 + i];
        acc[j] = fmaf(w4.x, tv0, acc[j]);
        acc[j] = fmaf(w4.y, tv1, acc[j]);
        acc[j] = fmaf(w4.z, tv2, acc[j]);
        acc[j] = fmaf(w4.w, tv3, acc[j]);
      }
    }
    #pragma unroll
    for (int j=0;j<4;j++) red[(eq*4+j)*64 + t] = acc[j];
    __syncthreads();
    if (tid < 64) {
      #pragma unroll
      for (int j=0;j<4;j++){
        int o = ob*4 + j;
        float v = red[j*64+tid]+red[(4+j)*64+tid]+red[(8+j)*64+tid]+red[(12+j)*64+tid];
        tp[((size_t)b*256+o)*64 + tid] = v + b2[o];
      }
    }
  }
}

__device__ inline void mm_tile(int blk, int tid,
    const ushort* __restrict__ Wb, const ushort* __restrict__ Inb,
    const float* __restrict__ bias, ushort* __restrict__ Out)
{
  int n = blk / 12, ob = blk - n*12;
  int lane = tid & 63, w = tid >> 6;
  int o0 = ob*64 + w*16;
  int r = lane & 15, kg = lane >> 4;
  const ushort* wp = Wb + (size_t)(o0 + r)*256 + kg*8;
  const ushort* ip = Inb + ((size_t)n*64 + r)*256 + kg*8;
  f32x4 acc[4];
  #pragma unroll
  for (int j=0;j<4;j++) acc[j] = (f32x4){0.f,0.f,0.f,0.f};
  #pragma unroll
  for (int ks = 0; ks < 8; ks++) {
    bf16x8 a = *(const bf16x8*)(wp + ks*32);
    #pragma unroll
    for (int j = 0; j < 4; j++) {
      bf16x8 b = *(const bf16x8*)(ip + (size_t)j*16*256 + ks*32);
      acc[j] = __builtin_amdgcn_mfma_f32_16x16x32_bf16(a, b, acc[j], 0, 0, 0);
    }
  }
  #pragma unroll
  for (int j = 0; j < 4; j++) {
    #pragma unroll
    for (int rr = 0; rr < 4; rr++) {
      int o = o0 + kg*4 + rr;
      size_t idx = ((size_t)n*768 + o)*64 + j*16 + r;
      float v = acc[j][rr] + bias[o];
      if (o < 512) v *= 0.42044820762685725f;  // 32^-0.25
      Out[idx] = f2bf(v);
    }
  }
}

// wa MFMA with halved E-buffer: Ebuf[64 s][128 i] bf16 (16 KB), 2 K-half passes.
__device__ inline void wamm_tile(int blk2, int tid, char* smemc,
    const int* __restrict__ fi, const float* __restrict__ w1,
    const float* __restrict__ b1, const float* __restrict__ tp,
    const ushort* __restrict__ w3b, const float* __restrict__ b3,
    ushort* __restrict__ ew)
{
  int oh = blk2 & 1; int bt = blk2 >> 1;
  int b = bt >> 6, t = bt & 63;
  float* l0 = (float*)smemc;
  float* l1 = l0 + 64;
  float* l2 = l1 + 64;
  ushort* Ebuf = (ushort*)(smemc + 768);   // [64 s][128 i] chunk-swizzled
  if (tid < 64){
    int rel = fi[b*64+tid] - fi[b*64+t];
    float r0 = rel>0 ? (float)rel   : 0.f;
    float r1 = rel<0 ? (float)(-rel): 0.f;
    l0[tid] = log1pf(r0);
    l1[tid] = log1pf(r1);
    l2[tid] = (rel==0) ? 0.6931471805599453f : 0.f;
  }
  __syncthreads();
  int s = tid & 63;
  int iq = __builtin_amdgcn_readfirstlane(tid >> 6);
  float L0 = l0[s], L1 = l1[s], L2 = l2[s];
  int lane = tid & 63, w = tid >> 6;
  int r = lane & 15, kg = lane >> 4;
  int o0 = oh*128 + w*32;
  f32x4 acc[2][4];
  #pragma unroll
  for (int m=0;m<2;m++)
    #pragma unroll
    for (int j=0;j<4;j++) acc[m][j] = (f32x4){0.f,0.f,0.f,0.f};
  #pragma unroll
  for (int half = 0; half < 2; half++){
    if (half) __syncthreads();           // prior MFMA reads of Ebuf done
    #pragma unroll
    for (int c4 = 0; c4 < 4; c4++){
      int cl = iq*4 + c4;                // chunk_local 0..15 (wave-uniform)
      int i0 = half*128 + cl*8;
      u16x8 pack;
      #pragma unroll
      for (int e = 0; e < 8; e++){
        int i = i0 + e;
        float bb = b1[i] + tp[((size_t)b*256 + i)*64 + t];
        float evv = fmaf(w1[i*3], L0, fmaf(w1[i*3+1], L1, fmaf(w1[i*3+2], L2, bb)));
        pack[e] = f2bf(fmaxf(evv, 0.f));
      }
      int csw = cl ^ (s & 15);
      *(u16x8*)&Ebuf[s*128 + csw*8] = pack;
    }
    __syncthreads();
    #pragma unroll
    for (int k4 = 0; k4 < 4; k4++){
      int ks8 = half*4 + k4;
      bf16x8 a0 = *(const bf16x8*)(w3b + (size_t)(o0 +      r)*256 + kg*8 + ks8*32);
      bf16x8 a1 = *(const bf16x8*)(w3b + (size_t)(o0 + 16 + r)*256 + kg*8 + ks8*32);
      #pragma unroll
      for (int j=0;j<4;j++){
        int srow = j*16 + r;
        int cl = (kg + k4*4) ^ (srow & 15);
        bf16x8 bfr = *(const bf16x8*)&Ebuf[srow*128 + cl*8];
        acc[0][j] = __builtin_amdgcn_mfma_f32_16x16x32_bf16(a0, bfr, acc[0][j], 0, 0, 0);
        acc[1][j] = __builtin_amdgcn_mfma_f32_16x16x32_bf16(a1, bfr, acc[1][j], 0, 0, 0);
      }
    }
  }
  #pragma unroll
  for (int m=0;m<2;m++){
    #pragma unroll
    for (int j=0;j<4;j++){
      #pragma unroll
      for (int rr=0;rr<4;rr++){
        int o = o0 + m*16 + kg*4 + rr;
        int scol = j*16 + r;
        ew[((size_t)(b*256+o))*4096 + t*64 + scol] = f2bf(__expf(acc[m][j][rr] + b3[o]));
      }
    }
  }
}

__device__ inline void scores_tile(int blk, int tid, char* smemc,
    const ushort* __restrict__ qkv, ushort* __restrict__ es,
    const float* __restrict__ amask)
{
  int n = blk >> 3, hh = blk & 7;
  float* qs = (float*)smemc;
  float* ks = qs + 2048;
  const ushort* base = qkv + (size_t)n*(768*64);
  for (int i=tid; i<2048; i+=256){
    int cq = i>>6, tt = i&63;
    qs[i] = bf2f(base[(cq*8+hh)*64 + tt]);
    ks[i] = bf2f(base[(256 + cq*8+hh)*64 + tt]);
  }
  __syncthreads();
  int s  = tid & 63;
  int t4 = __builtin_amdgcn_readfirstlane(tid>>6);
  float msk = amask[(n >> 5)*64 + s];
  float acc[16];
  #pragma unroll
  for (int j=0;j<16;j++) acc[j]=0.f;
  for (int cq=0;cq<32;cq++){
    float kv = ks[cq*64+s];
    #pragma unroll
    for (int j=0;j<16;j++) acc[j] = fmaf(qs[cq*64 + t4*16 + j], kv, acc[j]);
  }
  ushort* op = es + (size_t)blk*4096;
  #pragma unroll
  for (int j=0;j<16;j++)
    op[(t4*16+j)*64 + s] = f2bf(msk > 0.f ? __expf(acc[j]) : 0.f);
}

__device__ inline void attn_tile(int i, int tid, char* smemc,
    const ushort* __restrict__ es, const ushort* __restrict__ ew,
    const ushort* __restrict__ qkv, ushort* __restrict__ hv1)
{
  int xcd = i & 7, j0 = i >> 3;
  int g = xcd + ((j0 >> 6) << 3);
  int w64 = j0 & 63;
  int b = g >> 3, hh = g & 7;
  int dq = w64 >> 3, cs = w64 & 7;
  int t  = tid & 63;
  int dj = __builtin_amdgcn_readfirstlane(tid >> 6);
  int n  = b*D_ + dq*4 + dj;
  float4 (*ewl)[16] = (float4(*)[16])smemc;           // 16 KB
  float4 (*vl4)[16] = (float4(*)[16])(smemc + 16384); // 1 KB
  float4 esr[16];
  {
    const u16x8* sp = (const u16x8*)(es + ((size_t)(n*8 + hh))*4096 + (size_t)t*64);
    #pragma unroll
    for (int k8=0;k8<8;k8++){
      u16x8 e8 = sp[k8];
      float4 lo, hi;
      lo.x=bf2f(e8[0]); lo.y=bf2f(e8[1]); lo.z=bf2f(e8[2]); lo.w=bf2f(e8[3]);
      hi.x=bf2f(e8[4]); hi.y=bf2f(e8[5]); hi.z=bf2f(e8[6]); hi.w=bf2f(e8[7]);
      esr[2*k8] = lo; esr[2*k8+1] = hi;
    }
  }
  int vd = tid >> 4, vk = tid & 15;
  u16x8 rew[2]; ushort4 rv;
  {
    int c = cs*32 + hh;
    const u16x8* wap = (const u16x8*)(ew + ((size_t)(b*256 + c))*4096);
    rew[0] = wap[tid]; rew[1] = wap[tid+256];
    if (tid < 64)
      rv = *(const ushort4*)(qkv + ((size_t)(b*D_ + dq*4 + vd)*768 + 512 + c)*64 + 4*vk);
  }
  for (int ci=0; ci<4; ci++){
    __syncthreads();
    #pragma unroll
    for (int i2=0;i2<2;i2++){
      int ch = tid + 256*i2;
      int tr = ch >> 3, k8 = ch & 7;
      u16x8 e8 = rew[i2];
      float4 lo, hi;
      lo.x=bf2f(e8[0]); lo.y=bf2f(e8[1]); lo.z=bf2f(e8[2]); lo.w=bf2f(e8[3]);
      hi.x=bf2f(e8[4]); hi.y=bf2f(e8[5]); hi.z=bf2f(e8[6]); hi.w=bf2f(e8[7]);
      ewl[tr][(k8*2)   ^ (tr & 15)] = lo;
      ewl[tr][(k8*2+1) ^ (tr & 15)] = hi;
    }
    if (tid < 64){
      float4 vv; vv.x=bf2f(rv.x); vv.y=bf2f(rv.y); vv.z=bf2f(rv.z); vv.w=bf2f(rv.w);
      vl4[vd][vk] = vv;
    }
    __syncthreads();
    if (ci < 3){
      int c = (cs*4 + ci + 1)*8 + hh;
      const u16x8* wap = (const u16x8*)(ew + ((size_t)(b*256 + c))*4096);
      rew[0] = wap[tid]; rew[1] = wap[tid+256];
      if (tid < 64)
        rv = *(const ushort4*)(qkv + ((size_t)(b*D_ + dq*4 + vd)*768 + 512 + c)*64 + 4*vk);
    }
    float sum = 0.f;
    float ax=0.f, ay=0.f, az=0.f, aw=0.f;
    #pragma unroll
    for (int k=0;k<16;k++){
      float4 e4 = esr[k];
      float4 w4 = ewl[t][k ^ (t & 15)];
      float4 v4 = vl4[dj][k];
      float px = e4.x*w4.x, py = e4.y*w4.y, pz = e4.z*w4.z, pw = e4.w*w4.w;
      sum += px+py+pz+pw;
      ax = fmaf(px, v4.x, ax);
      ay = fmaf(py, v4.y, ay);
      az = fmaf(pz, v4.z, az);
      aw = fmaf(pw, v4.w, aw);
    }
    float acc = (ax+ay)+(az+aw);
    int cq = cs*4 + ci;
    hv1[(((size_t)n*8 + hh)*32 + cq)*64 + t] = f2bf(acc / sum);
  }
}

__device__ inline void proj_tile(int blk, int tid,
    const ushort* __restrict__ Wr, const ushort* __restrict__ hv1,
    const float* __restrict__ bias, const float* __restrict__ resid,
    float* __restrict__ Out)
{
  int n = blk >> 2, ob = blk & 3;
  int lane = tid & 63, w = tid >> 6;
  int o0 = ob*64 + w*16;
  int r = lane & 15, kg = lane >> 4;
  const ushort* wp = Wr + (size_t)(o0 + r)*256 + kg*8;
  f32x4 acc[4];
  #pragma unroll
  for (int j=0;j<4;j++) acc[j] = (f32x4){0.f,0.f,0.f,0.f};
  #pragma unroll
  for (int ks = 0; ks < 8; ks++) {       // ks = h
    bf16x8 a = *(const bf16x8*)(wp + ks*32);
    #pragma unroll
    for (int j = 0; j < 4; j++) {
      const ushort* bp = hv1 + (((size_t)n*8 + ks)*32 + kg*8)*64 + (j*16 + r);
      bf16x8 bfr;
      #pragma unroll
      for (int e=0;e<8;e++) bfr[e] = (short)bp[(size_t)e*64];
      acc[j] = __builtin_amdgcn_mfma_f32_16x16x32_bf16(a, bfr, acc[j], 0, 0, 0);
    }
  }
  #pragma unroll
  for (int j = 0; j < 4; j++) {
    #pragma unroll
    for (int rr = 0; rr < 4; rr++) {
      int o = o0 + kg*4 + rr;
      size_t idx = ((size_t)n*256 + o)*64 + j*16 + r;
      Out[idx] = acc[j][rr] + bias[o] + resid[idx];
    }
  }
}

// ---------------------------------------------------------------- mega kernel
// __launch_bounds__(256, 2): min 2 waves/SIMD -> VGPR capped at 256 ->
// guaranteed 2 blocks/CU co-residency for NBLK=512 (the round-9/10 failure).
__global__ __launch_bounds__(256, 2) void k_mega(
    const float* __restrict__ x, const float* __restrict__ temb,
    const int* __restrict__ fi, const float* __restrict__ amask,
    const float* __restrict__ nsc, const float* __restrict__ nbi,
    const float* __restrict__ w_qkv, const float* __restrict__ b_qkv,
    const float* __restrict__ w1, const float* __restrict__ b1,
    const float* __restrict__ w2, const float* __restrict__ b2,
    const float* __restrict__ w3, const float* __restrict__ b3,
    const float* __restrict__ wp, const float* __restrict__ bp,
    ushort* __restrict__ qkvb, float* __restrict__ tpb,
    ushort* __restrict__ esb, ushort* __restrict__ ewb,
    ushort* __restrict__ htb, ushort* __restrict__ hvb,
    ushort* __restrict__ wqb, ushort* __restrict__ wprb,
    ushort* __restrict__ w3b, float* __restrict__ out,
    int* __restrict__ bar)
{
  __shared__ __align__(16) char smem[20608];
  int bid = blockIdx.x;
  int tid = threadIdx.x;

  // stage 1: casts + groupnorm + tproj (2496 tiles)
  for (int tile = bid; tile < 2496; tile += NBLK){
    prep_tile(tile, tid, smem, w_qkv, wp, w3, wqb, wprb, w3b,
              x, nsc, nbi, htb, temb, w2, b2, tpb);
    __syncthreads();
  }
  if (!gsync(bar, 0)) return;

  // stage 2: qkv GEMM (768 tiles) || wamm (256 tiles)
  for (int tile = bid; tile < 1024; tile += NBLK){
    if (tile < 768) mm_tile(tile, tid, wqb, htb, b_qkv, qkvb);
    else            wamm_tile(tile - 768, tid, smem, fi, w1, b1, tpb, w3b, b3, ewb);
    __syncthreads();
  }
  if (!gsync(bar, 1)) return;

  // stage 3: scores -> es (512 tiles)
  scores_tile(bid, tid, smem, qkvb, esb, amask);
  if (!gsync(bar, 2)) return;

  // stage 4: softmax + PV (1024 tiles)
  for (int tile = bid; tile < 1024; tile += NBLK){
    attn_tile(tile, tid, smem, esb, ewb, qkvb, hvb);
    __syncthreads();
  }
  if (!gsync(bar, 3)) return;

  // stage 5: proj GEMM + residual (256 tiles)
  if (bid < 256)
    proj_tile(bid, tid, wprb, hvb, bp, x, out);
}

extern "C" void kernel_launch(void* const* d_in, const int* in_sizes, int n_in,
                              void* d_out, int out_size, void* d_ws, size_t ws_size,
                              hipStream_t stream) {
  const float* x     = (const float*)d_in[0];
  const float* temb  = (const float*)d_in[1];
  const int*   fi    = (const int*)  d_in[2];
  const float* amask = (const float*)d_in[3];
  const float* nsc   = (const float*)d_in[4];
  const float* nbi   = (const float*)d_in[5];
  const float* w_qkv = (const float*)d_in[6];
  const float* b_qkv = (const float*)d_in[7];
  const float* w1    = (const float*)d_in[8];
  const float* b1    = (const float*)d_in[9];
  const float* w2    = (const float*)d_in[10];
  const float* b2    = (const float*)d_in[11];
  const float* w3    = (const float*)d_in[12];
  const float* b3    = (const float*)d_in[13];
  const float* wp    = (const float*)d_in[14];
  const float* bp    = (const float*)d_in[15];
  float* out = (float*)d_out;

  ushort* qkvb = (ushort*)d_ws;               // 3,145,728 us
  float*  tpb  = (float*)(qkvb + 3145728);    //    32,768 f
  ushort* esb  = (ushort*)(tpb + 32768);      // 2,097,152 us
  ushort* ewb  = esb + 2097152;               // 2,097,152 us
  ushort* htb  = ewb + 2097152;               // 1,048,576 us
  ushort* hvb  = htb + 1048576;               // 1,048,576 us
  ushort* wqb  = hvb + 1048576;               //   196,608 us
  ushort* wprb = wqb + 196608;                //    65,536 us
  ushort* w3b  = wprb + 65536;                //    65,536 us
  int*    bar  = (int*)(w3b + 65536);         //         8 int

  hipMemsetAsync(bar, 0, 8*sizeof(int), stream);
  k_mega<<<NBLK, 256, 0, stream>>>(x, temb, fi, amask, nsc, nbi,
                                   w_qkv, b_qkv, w1, b1, w2, b2, w3, b3, wp, bp,
                                   qkvb, tpb, esb, ewb, htb, hvb,
                                   wqb, wprb, w3b, out, bar);
}

// Round 13
// 65.890 us; speedup vs baseline: 4.9153x; 4.9153x over previous
//
#include <hip/hip_runtime.h>

#define B_ 2
#define D_ 32
#define C_ 256
#define T_ 64
#define TE_ 1024
#define H_ 8
#define N_ 64   // B_*D_

typedef __attribute__((ext_vector_type(8))) short bf16x8;
typedef __attribute__((ext_vector_type(8))) unsigned short u16x8;
typedef __attribute__((ext_vector_type(4))) float f32x4;

__device__ inline ushort f2bf(float x){
  unsigned u = __float_as_uint(x);
  unsigned r = u + 0x7FFFu + ((u>>16)&1u);
  return (ushort)(r>>16);
}
__device__ inline float bf2f(ushort u){
  return __uint_as_float(((unsigned)u)<<16);
}

// ---------------------------------------------------------------- prep
// blocks [0,192): cast w_qkv | [192,256): cast wp -> Wr (K'=h*32+cq reorder)
// [256,320): cast w3 | [320,2368): groupnorm | [2368,2496): tproj
__global__ __launch_bounds__(256) void k_prep(
    const float* __restrict__ w_qkv, const float* __restrict__ wp,
    const float* __restrict__ w3,
    ushort* __restrict__ wqb, ushort* __restrict__ wpr, ushort* __restrict__ w3b,
    const float* __restrict__ x, const float* __restrict__ nsc,
    const float* __restrict__ nbi, ushort* __restrict__ ht,
    const float* __restrict__ temb, const float* __restrict__ w2,
    const float* __restrict__ b2, float* __restrict__ tp)
{
  __shared__ float smem[5120];
  int blk = blockIdx.x;
  int tid = threadIdx.x;
  if (blk < 320) {
    if (blk < 192) {
      int i = blk*256 + tid;
      float4 v = ((const float4*)w_qkv)[i];
      ushort4 o; o.x=f2bf(v.x); o.y=f2bf(v.y); o.z=f2bf(v.z); o.w=f2bf(v.w);
      ((ushort4*)wqb)[i] = o;
    } else if (blk < 256) {
      // wp [o][c] -> Wr [o][(c&7)*32 + (c>>3)]
      int i = (blk-192)*256 + tid;
      float4 v = ((const float4*)wp)[i];
      int o = i >> 6, c0 = (i & 63)*4;
      #pragma unroll
      for (int e=0;e<4;e++){
        int c = c0+e;
        float vv = (e==0)?v.x:(e==1)?v.y:(e==2)?v.z:v.w;
        wpr[o*256 + (c&7)*32 + (c>>3)] = f2bf(vv);
      }
    } else {
      int i = (blk-256)*256 + tid;
      float4 v = ((const float4*)w3)[i];
      ushort4 o; o.x=f2bf(v.x); o.y=f2bf(v.y); o.z=f2bf(v.z); o.w=f2bf(v.w);
      ((ushort4*)w3b)[i] = o;
    }
    return;
  }
  if (blk < 2368) {
    // group norm: x (N,256,64) -> ht bf16 [n][t][c], 16B stores
    int b2k = blk - 320;
    int n = b2k >> 5, g = b2k & 31;
    const float* xp = x + ((size_t)n*C_ + g*8) * T_;
    float v0 = xp[tid], v1 = xp[tid+256];
    float s = v0+v1, ss = v0*v0 + v1*v1;
    #pragma unroll
    for (int off=32; off; off>>=1) { s += __shfl_down(s,off); ss += __shfl_down(ss,off); }
    float* red = smem;
    ushort* gbuf = (ushort*)(smem + 16);
    int wid = tid>>6, lane = tid&63;
    if (lane==0){ red[wid]=s; red[4+wid]=ss; }
    __syncthreads();
    if (tid==0){
      float a  = red[0]+red[1]+red[2]+red[3];
      float bb = red[4]+red[5]+red[6]+red[7];
      float mean = a*(1.f/512.f);
      float var  = bb*(1.f/512.f) - mean*mean;
      red[8]=mean; red[9]=rsqrtf(var + 1e-5f);
    }
    __syncthreads();
    float mean = red[8], inv = red[9];
    int t = tid & 63, w = tid >> 6;
    int c0 = g*8 + w, c1 = c0 + 4;
    gbuf[w*64 + t]     = f2bf((v0-mean)*inv*nsc[c0] + nbi[c0]);
    gbuf[(w+4)*64 + t] = f2bf((v1-mean)*inv*nsc[c1] + nbi[c1]);
    __syncthreads();
    if (tid < 64){
      u16x8 pk;
      #pragma unroll
      for (int i=0;i<8;i++) pk[i] = gbuf[i*64 + tid];
      *(u16x8*)&ht[((size_t)n*T_ + tid)*C_ + g*8] = pk;
    }
    return;
  }
  // tproj
  {
    int b3k = blk - 2368;
    int b = b3k >> 6, ob = b3k & 63;
    float* w2s = smem;
    float* red = smem + 4096;
    const float* w2p = w2 + (size_t)ob*4*1024;
    #pragma unroll
    for (int r = 0; r < 16; r++) w2s[r*256 + tid] = w2p[r*256 + tid];
    __syncthreads();
    int t = tid & 63, eq = tid >> 6;
    const float* tep = temb + ((size_t)b*1024 + eq*256)*64 + t;
    const float* wq  = w2s + eq*256;
    float acc[4] = {0.f,0.f,0.f,0.f};
    #pragma unroll 4
    for (int i = 0; i < 256; i += 4) {
      float tv0 = tep[(i+0)*64];
      float tv1 = tep[(i+1)*64];
      float tv2 = tep[(i+2)*64];
      float tv3 = tep[(i+3)*64];
      #pragma unroll
      for (int j = 0; j < 4; j++) {
        float4 w4 = *(const float4*)&wq[j*1024 + i];
        acc[j] = fmaf(w4.x, tv0, acc[j]);
        acc[j] = fmaf(w4.y, tv1, acc[j]);
        acc[j] = fmaf(w4.z, tv2, acc[j]);
        acc[j] = fmaf(w4.w, tv3, acc[j]);
      }
    }
    #pragma unroll
    for (int j=0;j<4;j++) red[(eq*4+j)*64 + t] = acc[j];
    __syncthreads();
    if (tid < 64) {
      #pragma unroll
      for (int j=0;j<4;j++){
        int o = ob*4 + j;
        float v = red[j*64+tid]+red[(4+j)*64+tid]+red[(8+j)*64+tid]+red[(12+j)*64+tid];
        tp[((size_t)b*256+o)*64 + tid] = v + b2[o];
      }
    }
  }
}

// ---------------------------------------------------------------- mm || wamm
// blocks [0,768): qkv GEMM (bf16 out, q/k pre-scaled)
// blocks [768,1024): wamm -> ew (bf16)    (independent of qkv; overlaps)
__global__ __launch_bounds__(256) void k_mw(
    const ushort* __restrict__ Wb, const ushort* __restrict__ Inb,
    const float* __restrict__ bias, ushort* __restrict__ Out,
    const int* __restrict__ fi, const float* __restrict__ w1,
    const float* __restrict__ b1, const float* __restrict__ tp,
    const ushort* __restrict__ w3b, const float* __restrict__ b3,
    ushort* __restrict__ ew)
{
  __shared__ char smem[33536];
  int blk = blockIdx.x;
  int tid = threadIdx.x;
  if (blk < 768) {
    // -------- qkv GEMM
    int n = blk / 12, ob = blk - n*12;
    int lane = tid & 63, w = tid >> 6;
    int o0 = ob*64 + w*16;
    int r = lane & 15, kg = lane >> 4;
    const ushort* wp = Wb + (size_t)(o0 + r)*256 + kg*8;
    const ushort* ip = Inb + ((size_t)n*64 + r)*256 + kg*8;
    f32x4 acc[4];
    #pragma unroll
    for (int j=0;j<4;j++) acc[j] = (f32x4){0.f,0.f,0.f,0.f};
    #pragma unroll
    for (int ks = 0; ks < 8; ks++) {
      bf16x8 a = *(const bf16x8*)(wp + ks*32);
      #pragma unroll
      for (int j = 0; j < 4; j++) {
        bf16x8 b = *(const bf16x8*)(ip + (size_t)j*16*256 + ks*32);
        acc[j] = __builtin_amdgcn_mfma_f32_16x16x32_bf16(a, b, acc[j], 0, 0, 0);
      }
    }
    #pragma unroll
    for (int j = 0; j < 4; j++) {
      #pragma unroll
      for (int rr = 0; rr < 4; rr++) {
        int o = o0 + kg*4 + rr;
        size_t idx = ((size_t)n*768 + o)*64 + j*16 + r;
        float v = acc[j][rr] + bias[o];
        if (o < 512) v *= 0.42044820762685725f;  // 32^-0.25
        Out[idx] = f2bf(v);
      }
    }
    return;
  }
  // -------- wamm -> ew (bf16)
  {
    int blk2 = blk - 768;              // ((b*64 + t)*2 + oh)
    int oh = blk2 & 1; int bt = blk2 >> 1;
    int b = bt >> 6, t = bt & 63;
    float* l0 = (float*)smem;
    float* l1 = l0 + 64;
    float* l2 = l1 + 64;
    ushort* Ebuf = (ushort*)(smem + 768);
    if (tid < 64){
      int rel = fi[b*64+tid] - fi[b*64+t];
      float r0 = rel>0 ? (float)rel   : 0.f;
      float r1 = rel<0 ? (float)(-rel): 0.f;
      l0[tid] = log1pf(r0);
      l1[tid] = log1pf(r1);
      l2[tid] = (rel==0) ? 0.6931471805599453f : 0.f;
    }
    __syncthreads();
    int s = tid & 63;
    int iq = __builtin_amdgcn_readfirstlane(tid >> 6);
    float L0 = l0[s], L1 = l1[s], L2 = l2[s];
    #pragma unroll
    for (int c8 = 0; c8 < 8; c8++){
      int chunk = iq*8 + c8;
      int ibase = chunk*8;
      u16x8 pack;
      #pragma unroll
      for (int e = 0; e < 8; e++){
        int i = ibase + e;
        float bb = b1[i] + tp[((size_t)b*256 + i)*64 + t];
        float evv = fmaf(w1[i*3], L0, fmaf(w1[i*3+1], L1, fmaf(w1[i*3+2], L2, bb)));
        pack[e] = f2bf(fmaxf(evv, 0.f));
      }
      int csw = chunk ^ (s & 31);
      *(u16x8*)&Ebuf[s*256 + csw*8] = pack;
    }
    __syncthreads();
    int lane = tid & 63, w = tid >> 6;
    int r = lane & 15, kg = lane >> 4;
    int o0 = oh*128 + w*32;
    f32x4 acc[2][4];
    #pragma unroll
    for (int m=0;m<2;m++)
      #pragma unroll
      for (int j=0;j<4;j++) acc[m][j] = (f32x4){0.f,0.f,0.f,0.f};
    #pragma unroll
    for (int ks8 = 0; ks8 < 8; ks8++){
      bf16x8 a0 = *(const bf16x8*)(w3b + (size_t)(o0 +      r)*256 + kg*8 + ks8*32);
      bf16x8 a1 = *(const bf16x8*)(w3b + (size_t)(o0 + 16 + r)*256 + kg*8 + ks8*32);
      #pragma unroll
      for (int j=0;j<4;j++){
        int srow = j*16 + r;
        int chunk = (kg + ks8*4) ^ (srow & 31);
        bf16x8 bfr = *(const bf16x8*)&Ebuf[srow*256 + chunk*8];
        acc[0][j] = __builtin_amdgcn_mfma_f32_16x16x32_bf16(a0, bfr, acc[0][j], 0, 0, 0);
        acc[1][j] = __builtin_amdgcn_mfma_f32_16x16x32_bf16(a1, bfr, acc[1][j], 0, 0, 0);
      }
    }
    #pragma unroll
    for (int m=0;m<2;m++){
      #pragma unroll
      for (int j=0;j<4;j++){
        #pragma unroll
        for (int rr=0;rr<4;rr++){
          int o = o0 + m*16 + kg*4 + rr;
          int scol = j*16 + r;
          ew[((size_t)(b*256+o))*4096 + t*64 + scol] = f2bf(__expf(acc[m][j][rr] + b3[o]));
        }
      }
    }
  }
}

// ---------------------------------------------------------------- scores
// es[n,h,t,s] = mask * exp(sum q*k)  (q,k bf16 pre-scaled)
__global__ __launch_bounds__(256) void k_scores(
    const ushort* __restrict__ qkv, ushort* __restrict__ es,
    const float* __restrict__ amask)
{
  __shared__ float qs[2048], ks[2048];
  int blk = blockIdx.x;
  int tid = threadIdx.x;
  int n = blk >> 3, hh = blk & 7;
  const ushort* base = qkv + (size_t)n*(768*64);
  for (int i=tid; i<2048; i+=256){
    int cq = i>>6, tt = i&63;
    qs[i] = bf2f(base[(cq*8+hh)*64 + tt]);
    ks[i] = bf2f(base[(256 + cq*8+hh)*64 + tt]);
  }
  __syncthreads();
  int s  = tid & 63;
  int t4 = __builtin_amdgcn_readfirstlane(tid>>6);
  float msk = amask[(n >> 5)*64 + s];
  float acc[16];
  #pragma unroll
  for (int j=0;j<16;j++) acc[j]=0.f;
  for (int cq=0;cq<32;cq++){
    float kv = ks[cq*64+s];
    #pragma unroll
    for (int j=0;j<16;j++) acc[j] = fmaf(qs[cq*64 + t4*16 + j], kv, acc[j]);
  }
  ushort* op = es + (size_t)blk*4096;
  #pragma unroll
  for (int j=0;j<16;j++)
    op[(t4*16+j)*64 + s] = f2bf(msk > 0.f ? __expf(acc[j]) : 0.f);
}

// ---------------------------------------------------------------- softmax+PV
// hv1[n][h][cq][t] (bf16). 2048 blocks (cs in [0,16), 2 c-tiles each) for
// 32 waves/CU latency hiding. XCD swizzle keeps each (b,h) group on one XCD.
__global__ __launch_bounds__(256) void k_attn(
    const ushort* __restrict__ es, const ushort* __restrict__ ew,
    const ushort* __restrict__ qkv, ushort* __restrict__ hv1)
{
  int i = blockIdx.x;            // 2048
  int xcd = i & 7, j0 = i >> 3;  // j0 in [0,256)
  int g = xcd + ((j0 >> 7) << 3);  // (b*8+h) group, 0..15
  int w128 = j0 & 127;
  int b = g >> 3, hh = g & 7;
  int dq = w128 >> 4, cs = w128 & 15;
  int tid = threadIdx.x;
  int t  = tid & 63;
  int dj = __builtin_amdgcn_readfirstlane(tid >> 6);
  int n  = b*D_ + dq*4 + dj;
  __shared__ float4 ewl[64][16];   // [t][k^(t&15)] swizzled
  __shared__ float4 vl4[4][16];
  float4 esr[16];
  {
    const u16x8* sp = (const u16x8*)(es + ((size_t)(n*8 + hh))*4096 + (size_t)t*64);
    #pragma unroll
    for (int k8=0;k8<8;k8++){
      u16x8 e8 = sp[k8];
      float4 lo, hi;
      lo.x=bf2f(e8[0]); lo.y=bf2f(e8[1]); lo.z=bf2f(e8[2]); lo.w=bf2f(e8[3]);
      hi.x=bf2f(e8[4]); hi.y=bf2f(e8[5]); hi.z=bf2f(e8[6]); hi.w=bf2f(e8[7]);
      esr[2*k8] = lo; esr[2*k8+1] = hi;
    }
  }
  int vd = tid >> 4, vk = tid & 15;          // v stage coords (tid<64)
  u16x8 rew[2]; ushort4 rv;
  // prologue: load tiles for ci=0
  {
    int c = cs*16 + hh;
    const u16x8* wap = (const u16x8*)(ew + ((size_t)(b*256 + c))*4096);
    rew[0] = wap[tid]; rew[1] = wap[tid+256];
    if (tid < 64)
      rv = *(const ushort4*)(qkv + ((size_t)(b*D_ + dq*4 + vd)*768 + 512 + c)*64 + 4*vk);
  }
  for (int ci=0; ci<2; ci++){
    __syncthreads();
    #pragma unroll
    for (int i2=0;i2<2;i2++){
      int ch = tid + 256*i2;           // chunk of 8 ushorts
      int tr = ch >> 3, k8 = ch & 7;
      u16x8 e8 = rew[i2];
      float4 lo, hi;
      lo.x=bf2f(e8[0]); lo.y=bf2f(e8[1]); lo.z=bf2f(e8[2]); lo.w=bf2f(e8[3]);
      hi.x=bf2f(e8[4]); hi.y=bf2f(e8[5]); hi.z=bf2f(e8[6]); hi.w=bf2f(e8[7]);
      ewl[tr][(k8*2)   ^ (tr & 15)] = lo;
      ewl[tr][(k8*2+1) ^ (tr & 15)] = hi;
    }
    if (tid < 64){
      float4 vv; vv.x=bf2f(rv.x); vv.y=bf2f(rv.y); vv.z=bf2f(rv.z); vv.w=bf2f(rv.w);
      vl4[vd][vk] = vv;
    }
    __syncthreads();
    if (ci < 1){
      int c = (cs*2 + ci + 1)*8 + hh;
      const u16x8* wap = (const u16x8*)(ew + ((size_t)(b*256 + c))*4096);
      rew[0] = wap[tid]; rew[1] = wap[tid+256];
      if (tid < 64)
        rv = *(const ushort4*)(qkv + ((size_t)(b*D_ + dq*4 + vd)*768 + 512 + c)*64 + 4*vk);
    }
    float sum = 0.f;
    float ax=0.f, ay=0.f, az=0.f, aw=0.f;
    #pragma unroll
    for (int k=0;k<16;k++){
      float4 e4 = esr[k];
      float4 w4 = ewl[t][k ^ (t & 15)];
      float4 v4 = vl4[dj][k];
      float px = e4.x*w4.x, py = e4.y*w4.y, pz = e4.z*w4.z, pw = e4.w*w4.w;
      sum += px+py+pz+pw;
      ax = fmaf(px, v4.x, ax);
      ay = fmaf(py, v4.y, ay);
      az = fmaf(pz, v4.z, az);
      aw = fmaf(pw, v4.w, aw);
    }
    float acc = (ax+ay)+(az+aw);
    int cq = cs*2 + ci;
    hv1[(((size_t)n*8 + hh)*32 + cq)*64 + t] = f2bf(acc / sum);
  }
}

// ---------------------------------------------------------------- proj GEMM
// Out[n,o,t] fp32 = sum_K' Wr[o,K'] * hv1[n][h=K'>>5][cq=K'&31][t] + bias + x
__global__ __launch_bounds__(256) void k_proj(
    const ushort* __restrict__ Wr, const ushort* __restrict__ hv1,
    const float* __restrict__ bias, const float* __restrict__ resid,
    float* __restrict__ Out)
{
  int blk = blockIdx.x;
  int n = blk >> 2, ob = blk & 3;
  int tid = threadIdx.x;
  int lane = tid & 63, w = tid >> 6;
  int o0 = ob*64 + w*16;
  int r = lane & 15, kg = lane >> 4;
  const ushort* wp = Wr + (size_t)(o0 + r)*256 + kg*8;
  f32x4 acc[4];
  #pragma unroll
  for (int j=0;j<4;j++) acc[j] = (f32x4){0.f,0.f,0.f,0.f};
  #pragma unroll
  for (int ks = 0; ks < 8; ks++) {       // ks = h
    bf16x8 a = *(const bf16x8*)(wp + ks*32);
    #pragma unroll
    for (int j = 0; j < 4; j++) {
      const ushort* bp = hv1 + (((size_t)n*8 + ks)*32 + kg*8)*64 + (j*16 + r);
      bf16x8 bfr;
      #pragma unroll
      for (int e=0;e<8;e++) bfr[e] = (short)bp[(size_t)e*64];
      acc[j] = __builtin_amdgcn_mfma_f32_16x16x32_bf16(a, bfr, acc[j], 0, 0, 0);
    }
  }
  #pragma unroll
  for (int j = 0; j < 4; j++) {
    #pragma unroll
    for (int rr = 0; rr < 4; rr++) {
      int o = o0 + kg*4 + rr;
      size_t idx = ((size_t)n*256 + o)*64 + j*16 + r;
      Out[idx] = acc[j][rr] + bias[o] + resid[idx];
    }
  }
}

extern "C" void kernel_launch(void* const* d_in, const int* in_sizes, int n_in,
                              void* d_out, int out_size, void* d_ws, size_t ws_size,
                              hipStream_t stream) {
  const float* x     = (const float*)d_in[0];
  const float* temb  = (const float*)d_in[1];
  const int*   fi    = (const int*)  d_in[2];
  const float* amask = (const float*)d_in[3];
  const float* nsc   = (const float*)d_in[4];
  const float* nbi   = (const float*)d_in[5];
  const float* w_qkv = (const float*)d_in[6];
  const float* b_qkv = (const float*)d_in[7];
  const float* w1    = (const float*)d_in[8];
  const float* b1    = (const float*)d_in[9];
  const float* w2    = (const float*)d_in[10];
  const float* b2    = (const float*)d_in[11];
  const float* w3    = (const float*)d_in[12];
  const float* b3    = (const float*)d_in[13];
  const float* wp    = (const float*)d_in[14];
  const float* bp    = (const float*)d_in[15];
  float* out = (float*)d_out;

  ushort* qkvb = (ushort*)d_ws;               // 3,145,728 us
  float*  tpb  = (float*)(qkvb + 3145728);    //    32,768 f
  ushort* esb  = (ushort*)(tpb + 32768);      // 2,097,152 us
  ushort* ewb  = esb + 2097152;               // 2,097,152 us
  ushort* htb  = ewb + 2097152;               // 1,048,576 us
  ushort* hvb  = htb + 1048576;               // 1,048,576 us
  ushort* wqb  = hvb + 1048576;               //   196,608 us
  ushort* wprb = wqb + 196608;                //    65,536 us
  ushort* w3b  = wprb + 65536;                //    65,536 us

  k_prep   <<<2496, 256, 0, stream>>>(w_qkv, wp, w3, wqb, wprb, w3b,
                                      x, nsc, nbi, htb, temb, w2, b2, tpb);
  k_mw     <<<1024, 256, 0, stream>>>(wqb, htb, b_qkv, qkvb,
                                      fi, w1, b1, tpb, w3b, b3, ewb);
  k_scores <<<512,  256, 0, stream>>>(qkvb, esb, amask);
  k_attn   <<<2048, 256, 0, stream>>>(esb, ewb, qkvb, hvb);
  k_proj   <<<N_*4, 256, 0, stream>>>(wprb, hvb, bp, x, out);
}

// Round 15
// 62.162 us; speedup vs baseline: 5.2101x; 1.0600x over previous
//
#include <hip/hip_runtime.h>

#define B_ 2
#define D_ 32
#define C_ 256
#define T_ 64
#define TE_ 1024
#define H_ 8
#define N_ 64   // B_*D_

typedef __attribute__((ext_vector_type(8))) short bf16x8;
typedef __attribute__((ext_vector_type(8))) unsigned short u16x8;
typedef __attribute__((ext_vector_type(4))) float f32x4;

__device__ inline ushort f2bf(float x){
  unsigned u = __float_as_uint(x);
  unsigned r = u + 0x7FFFu + ((u>>16)&1u);
  return (ushort)(r>>16);
}
__device__ inline float bf2f(ushort u){
  return __uint_as_float(((unsigned)u)<<16);
}

// ---------------------------------------------------------------- prep
// blocks [0,192): cast w_qkv | [192,256): cast wp -> Wr (K'=h*32+cq reorder)
// [256,320): cast w3 | [320,2368): groupnorm | [2368,2496): tproj
__global__ __launch_bounds__(256) void k_prep(
    const float* __restrict__ w_qkv, const float* __restrict__ wp,
    const float* __restrict__ w3,
    ushort* __restrict__ wqb, ushort* __restrict__ wpr, ushort* __restrict__ w3b,
    const float* __restrict__ x, const float* __restrict__ nsc,
    const float* __restrict__ nbi, ushort* __restrict__ ht,
    const float* __restrict__ temb, const float* __restrict__ w2,
    const float* __restrict__ b2, float* __restrict__ tp)
{
  __shared__ float smem[5120];
  int blk = blockIdx.x;
  int tid = threadIdx.x;
  if (blk < 320) {
    if (blk < 192) {
      int i = blk*256 + tid;
      float4 v = ((const float4*)w_qkv)[i];
      ushort4 o; o.x=f2bf(v.x); o.y=f2bf(v.y); o.z=f2bf(v.z); o.w=f2bf(v.w);
      ((ushort4*)wqb)[i] = o;
    } else if (blk < 256) {
      // wp [o][c] -> Wr [o][(c&7)*32 + (c>>3)]
      int i = (blk-192)*256 + tid;
      float4 v = ((const float4*)wp)[i];
      int o = i >> 6, c0 = (i & 63)*4;
      #pragma unroll
      for (int e=0;e<4;e++){
        int c = c0+e;
        float vv = (e==0)?v.x:(e==1)?v.y:(e==2)?v.z:v.w;
        wpr[o*256 + (c&7)*32 + (c>>3)] = f2bf(vv);
      }
    } else {
      int i = (blk-256)*256 + tid;
      float4 v = ((const float4*)w3)[i];
      ushort4 o; o.x=f2bf(v.x); o.y=f2bf(v.y); o.z=f2bf(v.z); o.w=f2bf(v.w);
      ((ushort4*)w3b)[i] = o;
    }
    return;
  }
  if (blk < 2368) {
    // group norm: x (N,256,64) -> ht bf16 [n][t][c], 16B stores
    int b2k = blk - 320;
    int n = b2k >> 5, g = b2k & 31;
    const float* xp = x + ((size_t)n*C_ + g*8) * T_;
    float v0 = xp[tid], v1 = xp[tid+256];
    float s = v0+v1, ss = v0*v0 + v1*v1;
    #pragma unroll
    for (int off=32; off; off>>=1) { s += __shfl_down(s,off); ss += __shfl_down(ss,off); }
    float* red = smem;
    ushort* gbuf = (ushort*)(smem + 16);
    int wid = tid>>6, lane = tid&63;
    if (lane==0){ red[wid]=s; red[4+wid]=ss; }
    __syncthreads();
    if (tid==0){
      float a  = red[0]+red[1]+red[2]+red[3];
      float bb = red[4]+red[5]+red[6]+red[7];
      float mean = a*(1.f/512.f);
      float var  = bb*(1.f/512.f) - mean*mean;
      red[8]=mean; red[9]=rsqrtf(var + 1e-5f);
    }
    __syncthreads();
    float mean = red[8], inv = red[9];
    int t = tid & 63, w = tid >> 6;
    int c0 = g*8 + w, c1 = c0 + 4;
    gbuf[w*64 + t]     = f2bf((v0-mean)*inv*nsc[c0] + nbi[c0]);
    gbuf[(w+4)*64 + t] = f2bf((v1-mean)*inv*nsc[c1] + nbi[c1]);
    __syncthreads();
    if (tid < 64){
      u16x8 pk;
      #pragma unroll
      for (int i=0;i<8;i++) pk[i] = gbuf[i*64 + tid];
      *(u16x8*)&ht[((size_t)n*T_ + tid)*C_ + g*8] = pk;
    }
    return;
  }
  // tproj
  {
    int b3k = blk - 2368;
    int b = b3k >> 6, ob = b3k & 63;
    float* w2s = smem;
    float* red = smem + 4096;
    const float* w2p = w2 + (size_t)ob*4*1024;
    #pragma unroll
    for (int r = 0; r < 16; r++) w2s[r*256 + tid] = w2p[r*256 + tid];
    __syncthreads();
    int t = tid & 63, eq = tid >> 6;
    const float* tep = temb + ((size_t)b*1024 + eq*256)*64 + t;
    const float* wq  = w2s + eq*256;
    float acc[4] = {0.f,0.f,0.f,0.f};
    #pragma unroll 4
    for (int i = 0; i < 256; i += 4) {
      float tv0 = tep[(i+0)*64];
      float tv1 = tep[(i+1)*64];
      float tv2 = tep[(i+2)*64];
      float tv3 = tep[(i+3)*64];
      #pragma unroll
      for (int j = 0; j < 4; j++) {
        float4 w4 = *(const float4*)&wq[j*1024 + i];
        acc[j] = fmaf(w4.x, tv0, acc[j]);
        acc[j] = fmaf(w4.y, tv1, acc[j]);
        acc[j] = fmaf(w4.z, tv2, acc[j]);
        acc[j] = fmaf(w4.w, tv3, acc[j]);
      }
    }
    #pragma unroll
    for (int j=0;j<4;j++) red[(eq*4+j)*64 + t] = acc[j];
    __syncthreads();
    if (tid < 64) {
      #pragma unroll
      for (int j=0;j<4;j++){
        int o = ob*4 + j;
        float v = red[j*64+tid]+red[(4+j)*64+tid]+red[(8+j)*64+tid]+red[(12+j)*64+tid];
        tp[((size_t)b*256+o)*64 + tid] = v + b2[o];
      }
    }
  }
}

// ---------------------------------------------------------------- mm || wamm
// blocks [0,768): qkv GEMM (bf16 out, q/k pre-scaled)
// blocks [768,1024): wamm -> ew (bf16)    (independent of qkv; overlaps)
__global__ __launch_bounds__(256) void k_mw(
    const ushort* __restrict__ Wb, const ushort* __restrict__ Inb,
    const float* __restrict__ bias, ushort* __restrict__ Out,
    const int* __restrict__ fi, const float* __restrict__ w1,
    const float* __restrict__ b1, const float* __restrict__ tp,
    const ushort* __restrict__ w3b, const float* __restrict__ b3,
    ushort* __restrict__ ew)
{
  __shared__ char smem[33536];
  int blk = blockIdx.x;
  int tid = threadIdx.x;
  if (blk < 768) {
    // -------- qkv GEMM
    int n = blk / 12, ob = blk - n*12;
    int lane = tid & 63, w = tid >> 6;
    int o0 = ob*64 + w*16;
    int r = lane & 15, kg = lane >> 4;
    const ushort* wp = Wb + (size_t)(o0 + r)*256 + kg*8;
    const ushort* ip = Inb + ((size_t)n*64 + r)*256 + kg*8;
    f32x4 acc[4];
    #pragma unroll
    for (int j=0;j<4;j++) acc[j] = (f32x4){0.f,0.f,0.f,0.f};
    #pragma unroll
    for (int ks = 0; ks < 8; ks++) {
      bf16x8 a = *(const bf16x8*)(wp + ks*32);
      #pragma unroll
      for (int j = 0; j < 4; j++) {
        bf16x8 b = *(const bf16x8*)(ip + (size_t)j*16*256 + ks*32);
        acc[j] = __builtin_amdgcn_mfma_f32_16x16x32_bf16(a, b, acc[j], 0, 0, 0);
      }
    }
    #pragma unroll
    for (int j = 0; j < 4; j++) {
      #pragma unroll
      for (int rr = 0; rr < 4; rr++) {
        int o = o0 + kg*4 + rr;
        size_t idx = ((size_t)n*768 + o)*64 + j*16 + r;
        float v = acc[j][rr] + bias[o];
        if (o < 512) v *= 0.42044820762685725f;  // 32^-0.25
        Out[idx] = f2bf(v);
      }
    }
    return;
  }
  // -------- wamm -> ew (bf16)
  {
    int blk2 = blk - 768;              // ((b*64 + t)*2 + oh)
    int oh = blk2 & 1; int bt = blk2 >> 1;
    int b = bt >> 6, t = bt & 63;
    float* l0 = (float*)smem;
    float* l1 = l0 + 64;
    float* l2 = l1 + 64;
    ushort* Ebuf = (ushort*)(smem + 768);
    if (tid < 64){
      int rel = fi[b*64+tid] - fi[b*64+t];
      float r0 = rel>0 ? (float)rel   : 0.f;
      float r1 = rel<0 ? (float)(-rel): 0.f;
      l0[tid] = log1pf(r0);
      l1[tid] = log1pf(r1);
      l2[tid] = (rel==0) ? 0.6931471805599453f : 0.f;
    }
    __syncthreads();
    int s = tid & 63;
    int iq = __builtin_amdgcn_readfirstlane(tid >> 6);
    float L0 = l0[s], L1 = l1[s], L2 = l2[s];
    #pragma unroll
    for (int c8 = 0; c8 < 8; c8++){
      int chunk = iq*8 + c8;
      int ibase = chunk*8;
      u16x8 pack;
      #pragma unroll
      for (int e = 0; e < 8; e++){
        int i = ibase + e;
        float bb = b1[i] + tp[((size_t)b*256 + i)*64 + t];
        float evv = fmaf(w1[i*3], L0, fmaf(w1[i*3+1], L1, fmaf(w1[i*3+2], L2, bb)));
        pack[e] = f2bf(fmaxf(evv, 0.f));
      }
      int csw = chunk ^ (s & 31);
      *(u16x8*)&Ebuf[s*256 + csw*8] = pack;
    }
    __syncthreads();
    int lane = tid & 63, w = tid >> 6;
    int r = lane & 15, kg = lane >> 4;
    int o0 = oh*128 + w*32;
    f32x4 acc[2][4];
    #pragma unroll
    for (int m=0;m<2;m++)
      #pragma unroll
      for (int j=0;j<4;j++) acc[m][j] = (f32x4){0.f,0.f,0.f,0.f};
    #pragma unroll
    for (int ks8 = 0; ks8 < 8; ks8++){
      bf16x8 a0 = *(const bf16x8*)(w3b + (size_t)(o0 +      r)*256 + kg*8 + ks8*32);
      bf16x8 a1 = *(const bf16x8*)(w3b + (size_t)(o0 + 16 + r)*256 + kg*8 + ks8*32);
      #pragma unroll
      for (int j=0;j<4;j++){
        int srow = j*16 + r;
        int chunk = (kg + ks8*4) ^ (srow & 31);
        bf16x8 bfr = *(const bf16x8*)&Ebuf[srow*256 + chunk*8];
        acc[0][j] = __builtin_amdgcn_mfma_f32_16x16x32_bf16(a0, bfr, acc[0][j], 0, 0, 0);
        acc[1][j] = __builtin_amdgcn_mfma_f32_16x16x32_bf16(a1, bfr, acc[1][j], 0, 0, 0);
      }
    }
    #pragma unroll
    for (int m=0;m<2;m++){
      #pragma unroll
      for (int j=0;j<4;j++){
        #pragma unroll
        for (int rr=0;rr<4;rr++){
          int o = o0 + m*16 + kg*4 + rr;
          int scol = j*16 + r;
          ew[((size_t)(b*256+o))*4096 + t*64 + scol] = f2bf(__expf(acc[m][j][rr] + b3[o]));
        }
      }
    }
  }
}

// ---------------------------------------------------------------- fused scores+softmax+PV
// Phase 1: per wave, recompute S = (q^T k) for n = b*32+dq*4+wid via MFMA,
//          apply mask+exp, store bf16 P-tile to chunk-XOR-swizzled LDS.
// Phase 2: thread (wid, t) reads its P-row into esr regs; LDS reused for
//          ewl/vl tiles; PV loop identical to validated round-8 body.
// 1024 blocks, XCD swizzle keeps each (b,h) group on one XCD.
__global__ __launch_bounds__(256) void k_attn2(
    const ushort* __restrict__ qkv, const ushort* __restrict__ ew,
    const float* __restrict__ amask, ushort* __restrict__ hv1)
{
  int i = blockIdx.x;            // 1024
  int xcd = i & 7, j0 = i >> 3;  // j0 in [0,128)
  int g = xcd + ((j0 >> 6) << 3);  // (b*8+h) group, 0..15
  int w64 = j0 & 63;
  int b = g >> 3, hh = g & 7;
  int dq = w64 >> 3, cs = w64 & 7;
  int tid = threadIdx.x;
  int lane = tid & 63;
  int wid = __builtin_amdgcn_readfirstlane(tid >> 6);
  int r = lane & 15, kg = lane >> 4;
  int n = b*D_ + dq*4 + wid;

  __shared__ __align__(16) char smem[33536];
  ushort* esl = (ushort*)smem;                        // [4][64][64] swz, 32 KB (phase 1)
  float4 (*ewl)[16] = (float4(*)[16])smem;            // 16 KB (phase 2, reuses esl)
  float4 (*vl4)[16] = (float4(*)[16])(smem + 16384);  // 1 KB  (phase 2)

  // ---- phase 1: QK^T -> exp -> esl
  {
    const ushort* qb = qkv + (size_t)n*(768*64);
    bf16x8 af[4], bfj[4];
    #pragma unroll
    for (int jt=0;jt<4;jt++){
      #pragma unroll
      for (int e=0;e<8;e++)   // A[t][cq] = q[cq][t], channel cq*8+hh
        af[jt][e] = (short)qb[(((kg*8+e)*8 + hh)*64) + jt*16 + r];
    }
    #pragma unroll
    for (int js=0;js<4;js++){
      #pragma unroll
      for (int e=0;e<8;e++)   // B[s][cq] = k[cq][s], channel 256+cq*8+hh
        bfj[js][e] = (short)qb[((256 + (kg*8+e)*8 + hh)*64) + js*16 + r];
    }
    float msk[4];
    #pragma unroll
    for (int js=0;js<4;js++) msk[js] = amask[b*64 + js*16 + r];
    #pragma unroll
    for (int jt=0;jt<4;jt++){
      #pragma unroll
      for (int js=0;js<4;js++){
        f32x4 acc = (f32x4){0.f,0.f,0.f,0.f};
        acc = __builtin_amdgcn_mfma_f32_16x16x32_bf16(af[jt], bfj[js], acc, 0, 0, 0);
        int s = js*16 + r;
        #pragma unroll
        for (int rr=0;rr<4;rr++){
          int t = jt*16 + kg*4 + rr;          // D: row=4*kg+rr, col=r (m89)
          float ev = msk[js] > 0.f ? __expf(acc[rr]) : 0.f;
          esl[((wid*64 + t)<<6) + (((s>>3) ^ (t&7))<<3) + (s&7)] = f2bf(ev);
        }
      }
    }
  }
  __syncthreads();
  // ---- read own P-row back into regs (same esr layout as round-8)
  int t = lane;
  float4 esr[16];
  #pragma unroll
  for (int k8=0;k8<8;k8++){
    u16x8 e8 = *(const u16x8*)&esl[((wid*64 + t)<<6) + ((k8 ^ (t&7))<<3)];
    float4 lo, hi;
    lo.x=bf2f(e8[0]); lo.y=bf2f(e8[1]); lo.z=bf2f(e8[2]); lo.w=bf2f(e8[3]);
    hi.x=bf2f(e8[4]); hi.y=bf2f(e8[5]); hi.z=bf2f(e8[6]); hi.w=bf2f(e8[7]);
    esr[2*k8] = lo; esr[2*k8+1] = hi;
  }
  __syncthreads();   // esl dead; smem reused for ewl/vl4

  // ---- phase 2: PV over 4 c-tiles (round-8 validated body)
  int dj = wid;
  int vd = tid >> 4, vk = tid & 15;
  u16x8 rew[2]; ushort4 rv;
  {
    int c = cs*32 + hh;
    const u16x8* wap = (const u16x8*)(ew + ((size_t)(b*256 + c))*4096);
    rew[0] = wap[tid]; rew[1] = wap[tid+256];
    if (tid < 64)
      rv = *(const ushort4*)(qkv + ((size_t)(b*D_ + dq*4 + vd)*768 + 512 + c)*64 + 4*vk);
  }
  for (int ci=0; ci<4; ci++){
    __syncthreads();
    #pragma unroll
    for (int i2=0;i2<2;i2++){
      int ch = tid + 256*i2;
      int tr = ch >> 3, k8 = ch & 7;
      u16x8 e8 = rew[i2];
      float4 lo, hi;
      lo.x=bf2f(e8[0]); lo.y=bf2f(e8[1]); lo.z=bf2f(e8[2]); lo.w=bf2f(e8[3]);
      hi.x=bf2f(e8[4]); hi.y=bf2f(e8[5]); hi.z=bf2f(e8[6]); hi.w=bf2f(e8[7]);
      ewl[tr][(k8*2)   ^ (tr & 15)] = lo;
      ewl[tr][(k8*2+1) ^ (tr & 15)] = hi;
    }
    if (tid < 64){
      float4 vv; vv.x=bf2f(rv.x); vv.y=bf2f(rv.y); vv.z=bf2f(rv.z); vv.w=bf2f(rv.w);
      vl4[vd][vk] = vv;
    }
    __syncthreads();
    if (ci < 3){
      int c = (cs*4 + ci + 1)*8 + hh;
      const u16x8* wap = (const u16x8*)(ew + ((size_t)(b*256 + c))*4096);
      rew[0] = wap[tid]; rew[1] = wap[tid+256];
      if (tid < 64)
        rv = *(const ushort4*)(qkv + ((size_t)(b*D_ + dq*4 + vd)*768 + 512 + c)*64 + 4*vk);
    }
    float sum = 0.f;
    float ax=0.f, ay=0.f, az=0.f, aw=0.f;
    #pragma unroll
    for (int k=0;k<16;k++){
      float4 e4 = esr[k];
      float4 w4 = ewl[t][k ^ (t & 15)];
      float4 v4 = vl4[dj][k];
      float px = e4.x*w4.x, py = e4.y*w4.y, pz = e4.z*w4.z, pw = e4.w*w4.w;
      sum += px+py+pz+pw;
      ax = fmaf(px, v4.x, ax);
      ay = fmaf(py, v4.y, ay);
      az = fmaf(pz, v4.z, az);
      aw = fmaf(pw, v4.w, aw);
    }
    float acc = (ax+ay)+(az+aw);
    int cq = cs*4 + ci;
    hv1[(((size_t)n*8 + hh)*32 + cq)*64 + t] = f2bf(acc / sum);
  }
}

// ---------------------------------------------------------------- proj GEMM
// Out[n,o,t] fp32 = sum_K' Wr[o,K'] * hv1[n][h=K'>>5][cq=K'&31][t] + bias + x
__global__ __launch_bounds__(256) void k_proj(
    const ushort* __restrict__ Wr, const ushort* __restrict__ hv1,
    const float* __restrict__ bias, const float* __restrict__ resid,
    float* __restrict__ Out)
{
  int blk = blockIdx.x;
  int n = blk >> 2, ob = blk & 3;
  int tid = threadIdx.x;
  int lane = tid & 63, w = tid >> 6;
  int o0 = ob*64 + w*16;
  int r = lane & 15, kg = lane >> 4;
  const ushort* wp = Wr + (size_t)(o0 + r)*256 + kg*8;
  f32x4 acc[4];
  #pragma unroll
  for (int j=0;j<4;j++) acc[j] = (f32x4){0.f,0.f,0.f,0.f};
  #pragma unroll
  for (int ks = 0; ks < 8; ks++) {       // ks = h
    bf16x8 a = *(const bf16x8*)(wp + ks*32);
    #pragma unroll
    for (int j = 0; j < 4; j++) {
      const ushort* bp = hv1 + (((size_t)n*8 + ks)*32 + kg*8)*64 + (j*16 + r);
      bf16x8 bfr;
      #pragma unroll
      for (int e=0;e<8;e++) bfr[e] = (short)bp[(size_t)e*64];
      acc[j] = __builtin_amdgcn_mfma_f32_16x16x32_bf16(a, bfr, acc[j], 0, 0, 0);
    }
  }
  #pragma unroll
  for (int j = 0; j < 4; j++) {
    #pragma unroll
    for (int rr = 0; rr < 4; rr++) {
      int o = o0 + kg*4 + rr;
      size_t idx = ((size_t)n*256 + o)*64 + j*16 + r;
      Out[idx] = acc[j][rr] + bias[o] + resid[idx];
    }
  }
}

extern "C" void kernel_launch(void* const* d_in, const int* in_sizes, int n_in,
                              void* d_out, int out_size, void* d_ws, size_t ws_size,
                              hipStream_t stream) {
  const float* x     = (const float*)d_in[0];
  const float* temb  = (const float*)d_in[1];
  const int*   fi    = (const int*)  d_in[2];
  const float* amask = (const float*)d_in[3];
  const float* nsc   = (const float*)d_in[4];
  const float* nbi   = (const float*)d_in[5];
  const float* w_qkv = (const float*)d_in[6];
  const float* b_qkv = (const float*)d_in[7];
  const float* w1    = (const float*)d_in[8];
  const float* b1    = (const float*)d_in[9];
  const float* w2    = (const float*)d_in[10];
  const float* b2    = (const float*)d_in[11];
  const float* w3    = (const float*)d_in[12];
  const float* b3    = (const float*)d_in[13];
  const float* wp    = (const float*)d_in[14];
  const float* bp    = (const float*)d_in[15];
  float* out = (float*)d_out;

  ushort* qkvb = (ushort*)d_ws;               // 3,145,728 us
  float*  tpb  = (float*)(qkvb + 3145728);    //    32,768 f
  ushort* ewb  = (ushort*)(tpb + 32768);      // 2,097,152 us
  ushort* htb  = ewb + 2097152;               // 1,048,576 us
  ushort* hvb  = htb + 1048576;               // 1,048,576 us
  ushort* wqb  = hvb + 1048576;               //   196,608 us
  ushort* wprb = wqb + 196608;                //    65,536 us
  ushort* w3b  = wprb + 65536;                //    65,536 us

  k_prep  <<<2496, 256, 0, stream>>>(w_qkv, wp, w3, wqb, wprb, w3b,
                                     x, nsc, nbi, htb, temb, w2, b2, tpb);
  k_mw    <<<1024, 256, 0, stream>>>(wqb, htb, b_qkv, qkvb,
                                     fi, w1, b1, tpb, w3b, b3, ewb);
  k_attn2 <<<1024, 256, 0, stream>>>(qkvb, ewb, amask, hvb);
  k_proj  <<<N_*4, 256, 0, stream>>>(wprb, hvb, bp, x, out);
}